// Round 2
// baseline (795.830 us; speedup 1.0000x reference)
//
#include <hip/hip_runtime.h>

#define N_NODES 100000
#define D_FEAT  64
#define N_EDGES 3200000
#define GAMMA   0.5f

// ---------------- CSR-build + gather path ----------------

__global__ void zero_counts_kernel(int* __restrict__ counts) {
    int i = blockIdx.x * blockDim.x + threadIdx.x;
    if (i < N_NODES) counts[i] = 0;
}

// histogram of dst; also zero the edge part of the output (fused)
__global__ void hist_kernel(const int* __restrict__ dst,
                            int* __restrict__ counts,
                            float* __restrict__ out_edge) {
    int i = blockIdx.x * blockDim.x + threadIdx.x;
    if (i < N_EDGES) {
        atomicAdd(&counts[dst[i]], 1);
        out_edge[i] = 0.0f;
    }
}

// single-workgroup exclusive scan over N_NODES counts -> offs[N+1], curs[N]
__global__ void scan_kernel(const int* __restrict__ counts,
                            int* __restrict__ offs,
                            int* __restrict__ curs) {
    __shared__ int part[1024];
    const int tid = threadIdx.x;
    const int C = (N_NODES + 1023) / 1024;   // 98
    int lo = tid * C;
    int hi = lo + C; if (hi > N_NODES) hi = N_NODES;
    int s = 0;
    for (int i = lo; i < hi; ++i) s += counts[i];
    part[tid] = s;
    __syncthreads();
    // Hillis-Steele inclusive scan
    for (int off = 1; off < 1024; off <<= 1) {
        int v = 0;
        if (tid >= off) v = part[tid - off];
        __syncthreads();
        part[tid] += v;
        __syncthreads();
    }
    int base = (tid > 0) ? part[tid - 1] : 0;
    for (int i = lo; i < hi; ++i) {
        offs[i] = base;
        curs[i] = base;
        base += counts[i];
    }
    if (tid == 0) offs[N_NODES] = part[1023];   // == N_EDGES
}

// scatter (src, e) records into dst-sorted bins
__global__ void scatter_kernel(const int* __restrict__ src,
                               const int* __restrict__ dst,
                               const float* __restrict__ e,
                               int* __restrict__ curs,
                               float2* __restrict__ recs) {
    int i = blockIdx.x * blockDim.x + threadIdx.x;
    if (i >= N_EDGES) return;
    int t = dst[i];
    int p = atomicAdd(&curs[t], 1);
    recs[p] = make_float2(__int_as_float(src[i]), e[i]);
}

// one 64-lane wave per node; lane = feature dim. Register accumulate,
// single coalesced write, fused -GAMMA*h0.
__global__ void gather_kernel(const float* __restrict__ h,
                              const int* __restrict__ offs,
                              const float2* __restrict__ recs,
                              float* __restrict__ out) {
    int n = blockIdx.x * (blockDim.x >> 6) + (threadIdx.x >> 6);
    int d = threadIdx.x & 63;
    if (n >= N_NODES) return;
    int lo = offs[n], hi = offs[n + 1];
    float acc = 0.0f;
    int k = lo;
    float2 r = (k < hi) ? recs[k] : make_float2(0.0f, 0.0f);
    while (k < hi) {
        float2 cur = r;
        ++k;
        if (k < hi) r = recs[k];          // prefetch next record
        int s = __float_as_int(cur.x);
        acc += h[s * D_FEAT + d] * cur.y; // coalesced 256B row gather
    }
    int o = n * D_FEAT + d;
    out[o] = acc - GAMMA * h[o];
}

// ---------------- fallback atomic path (if ws too small) ----------------

__global__ void init_out_kernel(const float* __restrict__ x,
                                float* __restrict__ out,
                                int nd, int total) {
    int i = blockIdx.x * blockDim.x + threadIdx.x;
    if (i < nd)         out[i] = -GAMMA * x[i];
    else if (i < total) out[i] = 0.0f;
}

__global__ void edge_scatter_kernel(const float* __restrict__ h,
                                    const float* __restrict__ e,
                                    const int* __restrict__ src,
                                    const int* __restrict__ dst,
                                    float* __restrict__ out) {
    long long idx = (long long)blockIdx.x * blockDim.x + threadIdx.x;
    int edge = (int)(idx >> 6);
    int d    = (int)(idx & 63);
    if (edge >= N_EDGES) return;
    int   s = src[edge];
    int   t = dst[edge];
    float w = e[edge];
    atomicAdd(&out[t * D_FEAT + d], h[s * D_FEAT + d] * w);
}

// ---------------- launch ----------------

extern "C" void kernel_launch(void* const* d_in, const int* in_sizes, int n_in,
                              void* d_out, int out_size, void* d_ws, size_t ws_size,
                              hipStream_t stream) {
    const float* x   = (const float*)d_in[1];
    const int*   src = (const int*)d_in[2];
    const int*   dst = (const int*)d_in[3];
    float*       out = (float*)d_out;

    const int nd = N_NODES * D_FEAT;

    // workspace layout: counts[N] | offs[N+1] | curs[N] | pad | recs[E] (float2)
    size_t ints   = (size_t)N_NODES * 3 + 1;
    size_t rec_off = (ints * 4 + 15) & ~(size_t)15;         // 16B align
    size_t needed  = rec_off + (size_t)N_EDGES * 8;

    if (ws_size >= needed) {
        int*    counts = (int*)d_ws;
        int*    offs   = counts + N_NODES;
        int*    curs   = offs + N_NODES + 1;
        float2* recs   = (float2*)((char*)d_ws + rec_off);

        zero_counts_kernel<<<(N_NODES + 255) / 256, 256, 0, stream>>>(counts);
        hist_kernel<<<(N_EDGES + 255) / 256, 256, 0, stream>>>(dst, counts, out + nd);
        scan_kernel<<<1, 1024, 0, stream>>>(counts, offs, curs);
        scatter_kernel<<<(N_EDGES + 255) / 256, 256, 0, stream>>>(src, dst, x + nd, curs, recs);
        gather_kernel<<<(N_NODES * 64 + 255) / 256, 256, 0, stream>>>(x, offs, recs, out);
    } else {
        // fallback: atomic scatter
        const int total = nd + N_EDGES;
        init_out_kernel<<<(total + 255) / 256, 256, 0, stream>>>(x, out, nd, total);
        long long threads = (long long)N_EDGES * 64;
        edge_scatter_kernel<<<(int)((threads + 255) / 256), 256, 0, stream>>>(
            x, x + nd, src, dst, out);
    }
}